// Round 1
// baseline (316.747 us; speedup 1.0000x reference)
//
#include <hip/hip_runtime.h>
#include <math.h>

// ---------------------------------------------------------------------------
// RecursiveEncoder forward, fp16 MFMA pipeline.
//   kconv : cast+transpose weights into ws (chunk-major, padded rows)
//   k1    : leaf encoder (f32 vector, K=10) + big GEMM (child_feats @ W1a,
//           MFMA f16) + sem-row gather + relu + masked max  -> xbuf (f16)
//   k2    : x @ W2 -> relu -> @ Ws1 -> relu -> @ Wmu / @ Wvar -> sampler
// ---------------------------------------------------------------------------

#define NPAR   32768      // B
#define LDA    264        // padded activation row (halfs): 2-way-free bank pattern
#define LDW    72         // padded weight-chunk row (halfs)
#define CELEMS (256*72)   // halfs per 64-wide K chunk of one transposed weight
#define WELEMS (4*CELEMS) // halfs per whole transposed weight (K=256)

typedef _Float16 f16;
typedef _Float16 f16x8 __attribute__((ext_vector_type(8)));
typedef float    f32x4 __attribute__((ext_vector_type(4)));

__device__ __forceinline__ void async16(const void* g, void* l) {
    __builtin_amdgcn_global_load_lds((const __attribute__((address_space(1))) void*)g,
                                     (__attribute__((address_space(3))) void*)l, 16, 0, 0);
}
__device__ __forceinline__ f32x4 mfma16(f16x8 a, f16x8 b, f32x4 c) {
    return __builtin_amdgcn_mfma_f32_16x16x32_f16(a, b, c, 0, 0, 0);
}

// ---------------- kconv: weights -> ws, layout [chunk c][n][kk(pad 72)] ------
// element = W[c*64+kk][n]  (i.e. transposed, k contiguous per n)
__global__ void kconv(const float* __restrict__ W1, const float* __restrict__ W2,
                      const float* __restrict__ Ws1, const float* __restrict__ Wmu,
                      const float* __restrict__ Wvar, f16* __restrict__ ws) {
    int idx = blockIdx.x * 256 + threadIdx.x;
    if (idx >= 5 * WELEMS) return;
    int w = idx / WELEMS, r = idx % WELEMS;
    int c = r / CELEMS;  int r2 = r % CELEMS;
    int n = r2 / LDW;    int kk = r2 % LDW;
    const float* s = W1;
    if (w == 1) s = W2; else if (w == 2) s = Ws1; else if (w == 3) s = Wmu; else if (w == 4) s = Wvar;
    float v = (kk < 64) ? s[(c * 64 + kk) * 256 + n] : 0.f;
    ws[idx] = (f16)v;
}

// ---------------- k1: leaf + big GEMM + max-pool -----------------------------
// block = 8 parents = 80 child rows; grid 4096; 256 thr (4 waves)
__global__ __launch_bounds__(256, 2)
void k1(const float* __restrict__ box, const float* __restrict__ Wbox,
        const float* __restrict__ bbox, const float* __restrict__ W1,
        const float* __restrict__ b1, const int* __restrict__ sem,
        const int* __restrict__ nch, const f16* __restrict__ w1t,
        f16* __restrict__ xbuf) {
    __shared__ __align__(16) char smem[79456];
    f16*   lA   = (f16*)smem;                       // [80][264] child_feats (leaf part)
    f16*   lB   = (f16*)(smem + 80 * LDA * 2);      // [256][72] weight chunk
    float* lbox = (float*)(smem + 80 * LDA * 2);    // [80][10], overlays lB (dead before chunk 0)
    int*   lsem = (int*)(smem + 80 * LDA * 2 + 256 * LDW * 2);        // 80
    int*   lnc  = (int*)(smem + 80 * LDA * 2 + 256 * LDW * 2 + 320);  // 8

    int tid = threadIdx.x, blk = blockIdx.x;

    for (int i = tid; i < 800; i += 256) lbox[i] = box[(size_t)blk * 800 + i];
    if (tid < 80) lsem[tid] = sem[blk * 80 + tid];
    if (tid < 8)  lnc[tid]  = nch[blk * 8 + tid];
    __syncthreads();

    // phase 0: leaf = relu(box @ Wbox + bbox), f32 vector (K=10), existing children only
    {
        float wc[10];
        #pragma unroll
        for (int i = 0; i < 10; i++) wc[i] = Wbox[i * 256 + tid];
        float bb = bbox[tid];
        for (int p = 0; p < 8; p++) {
            int nc = lnc[p];                       // wave-uniform
            for (int m = 0; m < nc; m++) {
                int r = p * 10 + m;
                float s = bb;
                #pragma unroll
                for (int i = 0; i < 10; i++) s = fmaf(lbox[r * 10 + i], wc[i], s);
                lA[r * LDA + tid] = (f16)fmaxf(s, 0.f);
            }
        }
    }

    int w = tid >> 6, lane = tid & 63, q = lane >> 4, r16 = lane & 15;
    f32x4 acc[5][4];
    #pragma unroll
    for (int mt = 0; mt < 5; mt++)
        #pragma unroll
        for (int nt = 0; nt < 4; nt++) acc[mt][nt] = (f32x4){0.f, 0.f, 0.f, 0.f};

    // K loop: feat_pre = leaf @ W1[0:256]
    for (int c = 0; c < 4; c++) {
        __syncthreads();                           // prev chunk consumed (& lbox dead at c=0)
        {
            const char* src = (const char*)(w1t + c * CELEMS);
            char* dst = (char*)lB;
            #pragma unroll
            for (int j = 0; j < 9; j++) { int o = (tid + j * 256) * 16; async16(src + o, dst + o); }
        }
        __syncthreads();                           // drains vmcnt
        #pragma unroll
        for (int k32 = 0; k32 < 64; k32 += 32) {
            f16x8 a[5], b[4];
            #pragma unroll
            for (int mt = 0; mt < 5; mt++)
                a[mt] = *(const f16x8*)&lA[(mt * 16 + r16) * LDA + c * 64 + k32 + q * 8];
            #pragma unroll
            for (int nt = 0; nt < 4; nt++)
                b[nt] = *(const f16x8*)&lB[(w * 64 + nt * 16 + r16) * LDW + k32 + q * 8];
            #pragma unroll
            for (int mt = 0; mt < 5; mt++)
                #pragma unroll
                for (int nt = 0; nt < 4; nt++) acc[mt][nt] = mfma16(a[mt], b[nt], acc[mt][nt]);
        }
    }
    __syncthreads();                               // all A reads done before overwrite

    // epilogue: + b1 + one-hot sem row of W1, relu -> lA (f16)
    #pragma unroll
    for (int mt = 0; mt < 5; mt++)
        #pragma unroll
        for (int nt = 0; nt < 4; nt++) {
            int col = w * 64 + nt * 16 + r16;
            float bv = b1[col];
            #pragma unroll
            for (int i = 0; i < 4; i++) {
                int row = mt * 16 + q * 4 + i;
                int sid = lsem[row];
                float v = acc[mt][nt][i] + bv + W1[(256 + sid) * 256 + col];
                lA[row * LDA + col] = (f16)fmaxf(v, 0.f);
            }
        }
    __syncthreads();

    // masked max over children -> xbuf (padded f16 rows)
    for (int p = 0; p < 8; p++) {
        int nc = lnc[p];
        float v = 0.f;
        for (int m = 0; m < nc; m++) v = fmaxf(v, (float)lA[(p * 10 + m) * LDA + tid]);
        xbuf[((size_t)blk * 8 + p) * LDA + tid] = (f16)v;
    }
}

// ---------------- k2: sampler chain ------------------------------------------
// block = 32 parents; grid 1024; 256 thr
__global__ __launch_bounds__(256, 2)
void k2(const f16* __restrict__ xbuf, const f16* __restrict__ w2t,
        const float* __restrict__ b2, const float* __restrict__ bs1,
        const float* __restrict__ bmu, const float* __restrict__ bvar,
        const float* __restrict__ eps, float* __restrict__ out) {
    __shared__ __align__(16) char smem[70656];
    f16* actA = (f16*)smem;                 // [32][264]
    f16* actB = (f16*)(smem + 16896);       // [32][264]
    f16* wbuf = (f16*)(smem + 33792);       // [256][72]

    int tid = threadIdx.x, blk = blockIdx.x;
    int w = tid >> 6, lane = tid & 63, q = lane >> 4, r16 = lane & 15;

    {   // stage x tile (contiguous padded rows)
        const char* src = (const char*)(xbuf + (size_t)blk * 32 * LDA);
        #pragma unroll
        for (int j = 0; j < 5; j++) {
            int idx = tid + j * 256;
            if (idx < 1056) async16(src + idx * 16, (char*)actA + idx * 16);
        }
    }

    f32x4 acc[2][4];
    auto gemm = [&](const f16* A, const f16* Wc) {
        #pragma unroll
        for (int mt = 0; mt < 2; mt++)
            #pragma unroll
            for (int nt = 0; nt < 4; nt++) acc[mt][nt] = (f32x4){0.f, 0.f, 0.f, 0.f};
        for (int c = 0; c < 4; c++) {
            __syncthreads();
            {
                const char* src = (const char*)(Wc + c * CELEMS);
                char* dst = (char*)wbuf;
                #pragma unroll
                for (int j = 0; j < 9; j++) { int o = (tid + j * 256) * 16; async16(src + o, dst + o); }
            }
            __syncthreads();
            #pragma unroll
            for (int k32 = 0; k32 < 64; k32 += 32) {
                f16x8 a[2], b[4];
                #pragma unroll
                for (int mt = 0; mt < 2; mt++)
                    a[mt] = *(const f16x8*)&A[(mt * 16 + r16) * LDA + c * 64 + k32 + q * 8];
                #pragma unroll
                for (int nt = 0; nt < 4; nt++)
                    b[nt] = *(const f16x8*)&wbuf[(w * 64 + nt * 16 + r16) * LDW + k32 + q * 8];
                #pragma unroll
                for (int mt = 0; mt < 2; mt++)
                    #pragma unroll
                    for (int nt = 0; nt < 4; nt++) acc[mt][nt] = mfma16(a[mt], b[nt], acc[mt][nt]);
            }
        }
    };

    const f16* Ws1t = w2t + WELEMS;
    const f16* Wmut = w2t + 2 * WELEMS;
    const f16* Wvart = w2t + 3 * WELEMS;

    // GEMM1: parent = relu(x @ W2 + b2) -> actB
    gemm(actA, w2t);
    #pragma unroll
    for (int mt = 0; mt < 2; mt++)
        #pragma unroll
        for (int nt = 0; nt < 4; nt++) {
            int col = w * 64 + nt * 16 + r16;
            float bv = b2[col];
            #pragma unroll
            for (int i = 0; i < 4; i++) {
                int row = mt * 16 + q * 4 + i;
                actB[row * LDA + col] = (f16)fmaxf(acc[mt][nt][i] + bv, 0.f);
            }
        }

    // GEMM2: enc = relu(parent @ Ws1 + bs1) -> actA
    gemm(actB, Ws1t);
    #pragma unroll
    for (int mt = 0; mt < 2; mt++)
        #pragma unroll
        for (int nt = 0; nt < 4; nt++) {
            int col = w * 64 + nt * 16 + r16;
            float bv = bs1[col];
            #pragma unroll
            for (int i = 0; i < 4; i++) {
                int row = mt * 16 + q * 4 + i;
                actA[row * LDA + col] = (f16)fmaxf(acc[mt][nt][i] + bv, 0.f);
            }
        }

    // GEMM3: mu (keep in regs)
    gemm(actA, Wmut);
    f32x4 mu[2][4];
    #pragma unroll
    for (int mt = 0; mt < 2; mt++)
        #pragma unroll
        for (int nt = 0; nt < 4; nt++) mu[mt][nt] = acc[mt][nt];

    // GEMM4: logvar + fused sampler epilogue
    gemm(actA, Wvart);
    #pragma unroll
    for (int mt = 0; mt < 2; mt++)
        #pragma unroll
        for (int nt = 0; nt < 4; nt++) {
            int col = w * 64 + nt * 16 + r16;
            float bm = bmu[col], bv = bvar[col];
            #pragma unroll
            for (int i = 0; i < 4; i++) {
                int row = mt * 16 + q * 4 + i;
                size_t grow = (size_t)blk * 32 + row;
                float m_ = mu[mt][nt][i] + bm;
                float lv = acc[mt][nt][i] + bv;
                float e  = expf(lv);
                float smp = eps[grow * 256 + col] * sqrtf(e) + m_;
                out[grow * 512 + col]       = smp;
                out[grow * 512 + 256 + col] = 1.f + lv - m_ * m_ - e;
            }
        }
}

// ---------------------------------------------------------------------------
extern "C" void kernel_launch(void* const* d_in, const int* in_sizes, int n_in,
                              void* d_out, int out_size, void* d_ws, size_t ws_size,
                              hipStream_t stream) {
    const float* box  = (const float*)d_in[0];
    const float* eps  = (const float*)d_in[1];
    const float* Wbox = (const float*)d_in[2];
    const float* bbox = (const float*)d_in[3];
    const float* W1   = (const float*)d_in[4];
    const float* b1   = (const float*)d_in[5];
    const float* W2   = (const float*)d_in[6];
    const float* b2   = (const float*)d_in[7];
    const float* Ws1  = (const float*)d_in[8];
    const float* bs1  = (const float*)d_in[9];
    const float* Wmu  = (const float*)d_in[10];
    const float* bmu  = (const float*)d_in[11];
    const float* Wvar = (const float*)d_in[12];
    const float* bvar = (const float*)d_in[13];
    const int*   sem  = (const int*)d_in[14];
    const int*   nch  = (const int*)d_in[15];

    f16* wsh  = (f16*)d_ws;
    f16* w1t  = wsh;                  // W1a^T
    f16* w2t  = wsh + WELEMS;         // W2^T, Ws1^T, Wmu^T, Wvar^T consecutive
    f16* xbuf = wsh + 5 * WELEMS;     // [NPAR][264] f16

    kconv<<<(5 * WELEMS + 255) / 256, 256, 0, stream>>>(W1, W2, Ws1, Wmu, Wvar, wsh);
    k1<<<NPAR / 8, 256, 0, stream>>>(box, Wbox, bbox, W1, b1, sem, nch, w1t, xbuf);
    k2<<<NPAR / 32, 256, 0, stream>>>(xbuf, w2t, b2, bs1, bmu, bvar, eps, (float*)d_out);
}